// Round 1
// baseline (491.571 us; speedup 1.0000x reference)
//
#include <hip/hip_runtime.h>
#include <hip/hip_bf16.h>
#include <stdint.h>

#define ENC_DIM 2048
#define DEC_DIM 512
#define ATT_DIM 512
#define BATCH   256
#define PIX     196
#define M_TOTAL (BATCH*PIX)   // 50176

typedef unsigned short u16;
typedef __attribute__((ext_vector_type(8))) short  bf16x8;
typedef __attribute__((ext_vector_type(4))) float  f32x4;

// ---------- helpers ----------
__device__ __forceinline__ void gll16(const void* g, void* l) {
    __builtin_amdgcn_global_load_lds(
        (const __attribute__((address_space(1))) unsigned int*)g,
        (__attribute__((address_space(3))) unsigned int*)l,
        16, 0, 0);
}

union Pack8 {
    uint4 u;
    __hip_bfloat16 h[8];
};

__device__ __forceinline__ uint4 cvt8(float4 a, float4 b) {
    Pack8 p;
    p.h[0] = __float2bfloat16(a.x); p.h[1] = __float2bfloat16(a.y);
    p.h[2] = __float2bfloat16(a.z); p.h[3] = __float2bfloat16(a.w);
    p.h[4] = __float2bfloat16(b.x); p.h[5] = __float2bfloat16(b.y);
    p.h[6] = __float2bfloat16(b.z); p.h[7] = __float2bfloat16(b.w);
    return p.u;
}

// ---------- kernel 1: W_enc fp32 -> bf16 ----------
__global__ void k_convert(const float* __restrict__ W, u16* __restrict__ Wb) {
    int idx = blockIdx.x * 256 + threadIdx.x;            // 131072 total, each does 8 elems
    const float4* s = (const float4*)W + (size_t)idx * 2;
    ((uint4*)Wb)[idx] = cvt8(s[0], s[1]);
}

// ---------- kernel 2: att2[b,a] = dec[b,:].W_dec[a,:] + b_enc[a] + b_dec[a] ----------
__global__ void k_att2(const float* __restrict__ dec, const float* __restrict__ Wd,
                       const float* __restrict__ b_enc, const float* __restrict__ b_dec,
                       float* __restrict__ att2f) {
    int b = blockIdx.x;
    int t = threadIdx.x;
    __shared__ float dec_s[DEC_DIM];
    ((float2*)dec_s)[t] = ((const float2*)(dec + (size_t)b * DEC_DIM))[t];
    __syncthreads();
    #pragma unroll
    for (int rep = 0; rep < 2; ++rep) {
        int a = t + rep * 256;
        const float4* w = (const float4*)(Wd + (size_t)a * DEC_DIM);
        float acc = 0.f;
        #pragma unroll 4
        for (int e = 0; e < DEC_DIM / 4; ++e) {
            float4 wv = w[e];
            float4 dv = ((const float4*)dec_s)[e];
            acc += wv.x * dv.x + wv.y * dv.y + wv.z * dv.z + wv.w * dv.w;
        }
        att2f[(size_t)b * ATT_DIM + a] = acc + b_enc[a] + b_dec[a];
    }
}

// ---------- kernel 3: fused GEMM + relu + W_full dot -> att partials ----------
// att1[row, a] = enc[row,:] . W_enc[a,:]   (row = b*196+p, K=2048)
// att_part[nb*2+wn][row] = sum_{a in wave cols} relu(att1+att2[b,a]) * W_full[a]
__global__ void k_gemm(const float* __restrict__ enc, const u16* __restrict__ Wb,
                       const float* __restrict__ att2f, const float* __restrict__ Wfull,
                       float* __restrict__ att_part) {
    const int wg = blockIdx.x;
    const int mb = wg >> 2, nb = wg & 3;     // 4 consecutive blocks share the A panel (L3 reuse)
    const int t = threadIdx.x;
    const int lane = t & 63, wave = t >> 6;
    const int wm = wave >> 1, wn = wave & 1; // 2x2 wave grid, wave tile 64x64
    const int fr = lane & 15, fq = lane >> 4;

    __shared__ u16 As[128 * 64];  // [row][k] bf16, 16 KB
    __shared__ u16 Bs[128 * 64];  // [col][k] bf16, 16 KB

    f32x4 acc[4][4];
    #pragma unroll
    for (int m = 0; m < 4; ++m)
        #pragma unroll
        for (int n = 0; n < 4; ++n)
            acc[m][n] = (f32x4){0.f, 0.f, 0.f, 0.f};

    // A staging (reg-staged, fp32->bf16): sweep s: row = s*32 + (t>>3), k-octet (t&7)
    const int ar = t >> 3;
    const int ak = (t & 7) * 8;
    const float* a_src = enc + (size_t)(mb * 128 + ar) * ENC_DIM + ak;
    u16* a_dst = As + ar * 64 + ak;

    // B staging via global_load_lds (dest = uniform base + lane*16)
    const int br = wave * 8 + (lane >> 3);
    const int bk = (lane & 7) * 8;
    const u16* b_src = Wb + (size_t)(nb * 128 + br) * ENC_DIM + bk;
    u16* b_dst = Bs + wave * 512;   // bytes: wave*1024 (+ s*4096), lane offset added by HW

    const u16* a_rd = As + (wm * 64 + fr) * 64 + fq * 8;
    const u16* b_rd = Bs + (wn * 64 + fr) * 64 + fq * 8;

    for (int kt = 0; kt < ENC_DIM / 64; ++kt) {
        __syncthreads();                       // previous tile's compute done
        const float* as = a_src + kt * 64;
        #pragma unroll
        for (int s = 0; s < 4; ++s) {
            float4 v0 = *(const float4*)(as + (size_t)s * 32 * ENC_DIM);
            float4 v1 = *(const float4*)(as + (size_t)s * 32 * ENC_DIM + 4);
            *(uint4*)(a_dst + s * 32 * 64) = cvt8(v0, v1);
        }
        const u16* bs = b_src + kt * 64;
        #pragma unroll
        for (int s = 0; s < 4; ++s)
            gll16(bs + (size_t)s * 32 * ENC_DIM, b_dst + s * 2048);
        __syncthreads();                       // staging drained (vmcnt+lgkm at barrier)

        #pragma unroll
        for (int ks = 0; ks < 2; ++ks) {
            bf16x8 af[4], bfr[4];
            #pragma unroll
            for (int m = 0; m < 4; ++m) af[m]  = *(const bf16x8*)(a_rd + m * 1024 + ks * 32);
            #pragma unroll
            for (int n = 0; n < 4; ++n) bfr[n] = *(const bf16x8*)(b_rd + n * 1024 + ks * 32);
            #pragma unroll
            for (int m = 0; m < 4; ++m)
                #pragma unroll
                for (int n = 0; n < 4; ++n)
                    acc[m][n] = __builtin_amdgcn_mfma_f32_16x16x32_bf16(af[m], bfr[n], acc[m][n], 0, 0, 0);
        }
    }

    // epilogue: C/D layout col = lane&15, row = (lane>>4)*4 + reg  [m89/m91]
    const int row_base = mb * 128 + wm * 64 + fq * 4;
    const int col_base = nb * 128 + wn * 64 + fr;
    float wf[4];
    #pragma unroll
    for (int n = 0; n < 4; ++n) wf[n] = Wfull[col_base + n * 16];

    #pragma unroll
    for (int m = 0; m < 4; ++m) {
        #pragma unroll
        for (int r = 0; r < 4; ++r) {
            const int grow = row_base + m * 16 + r;
            const int bidx = grow / PIX;
            const float* a2 = att2f + (size_t)bidx * ATT_DIM;
            float ssum = 0.f;
            #pragma unroll
            for (int n = 0; n < 4; ++n) {
                float v = acc[m][n][r] + a2[col_base + n * 16];
                v = fmaxf(v, 0.f);
                ssum += v * wf[n];
            }
            #pragma unroll
            for (int off = 1; off < 16; off <<= 1)
                ssum += __shfl_xor(ssum, off, 64);
            if (fr == 0)
                att_part[(size_t)(nb * 2 + wn) * M_TOTAL + grow] = ssum;
        }
    }
}

// ---------- kernel 4: per-b softmax over 196 + alpha-weighted enc reduction ----------
__global__ void k_soft(const float* __restrict__ att_part, const float* __restrict__ enc,
                       float* __restrict__ out) {
    const int b  = blockIdx.x >> 1;
    const int ec = blockIdx.x & 1;   // e-chunk of 1024
    const int t  = threadIdx.x;
    __shared__ float red[256];
    __shared__ float alpha_s[PIX];

    float myatt = -1e30f;
    if (t < PIX) {
        float s = 0.f;
        #pragma unroll
        for (int j = 0; j < 8; ++j) s += att_part[(size_t)j * M_TOTAL + b * PIX + t];
        myatt = s;
    }
    red[t] = myatt;
    __syncthreads();
    for (int o = 128; o > 0; o >>= 1) {
        if (t < o) red[t] = fmaxf(red[t], red[t + o]);
        __syncthreads();
    }
    const float mx = red[0];
    __syncthreads();
    float e = 0.f;
    if (t < PIX) e = __expf(myatt - mx);
    red[t] = e;
    __syncthreads();
    for (int o = 128; o > 0; o >>= 1) {
        if (t < o) red[t] += red[t + o];
        __syncthreads();
    }
    const float inv = 1.f / red[0];
    if (t < PIX) {
        float al = e * inv;
        alpha_s[t] = al;
        if (ec == 0) out[(size_t)BATCH * ENC_DIM + b * PIX + t] = al;   // alpha output
    }
    __syncthreads();

    float4 acc = {0.f, 0.f, 0.f, 0.f};
    const float* ebase = enc + (size_t)b * PIX * ENC_DIM + ec * 1024 + t * 4;
    #pragma unroll 4
    for (int p = 0; p < PIX; ++p) {
        float4 x = *(const float4*)(ebase + (size_t)p * ENC_DIM);
        float a = alpha_s[p];
        acc.x += a * x.x; acc.y += a * x.y; acc.z += a * x.z; acc.w += a * x.w;
    }
    *(float4*)(out + (size_t)b * ENC_DIM + ec * 1024 + t * 4) = acc;
}

extern "C" void kernel_launch(void* const* d_in, const int* in_sizes, int n_in,
                              void* d_out, int out_size, void* d_ws, size_t ws_size,
                              hipStream_t stream) {
    const float* enc    = (const float*)d_in[0];
    const float* dec    = (const float*)d_in[1];
    const float* W_enc  = (const float*)d_in[2];
    const float* b_enc  = (const float*)d_in[3];
    const float* W_dec  = (const float*)d_in[4];
    const float* b_dec  = (const float*)d_in[5];
    const float* W_full = (const float*)d_in[6];
    // d_in[7] (b_full) unused: softmax is shift-invariant, att is not an output.

    char* ws = (char*)d_ws;
    u16*   Wb    = (u16*)ws;                                    // 2 MB bf16 W_enc
    float* att2f = (float*)(ws + 2 * 1024 * 1024);              // 512 KB
    float* att_p = (float*)(ws + 2 * 1024 * 1024 + 512 * 1024); // 8 * 50176 * 4 B

    hipLaunchKernelGGL(k_convert, dim3(512),     dim3(256), 0, stream, W_enc, Wb);
    hipLaunchKernelGGL(k_att2,    dim3(256),     dim3(256), 0, stream, dec, W_dec, b_enc, b_dec, att2f);
    hipLaunchKernelGGL(k_gemm,    dim3(392 * 4), dim3(256), 0, stream, enc, Wb, att2f, W_full, att_p);
    hipLaunchKernelGGL(k_soft,    dim3(512),     dim3(256), 0, stream, att_p, enc, (float*)d_out);
}

// Round 2
// 460.650 us; speedup vs baseline: 1.0671x; 1.0671x over previous
//
#include <hip/hip_runtime.h>
#include <hip/hip_bf16.h>
#include <stdint.h>

#define ENC_DIM 2048
#define DEC_DIM 512
#define ATT_DIM 512
#define BATCH   256
#define PIX     196
#define M_TOTAL (BATCH*PIX)   // 50176

typedef unsigned short u16;
typedef __attribute__((ext_vector_type(8))) short  bf16x8;
typedef __attribute__((ext_vector_type(4))) float  f32x4;

// ---------- helpers ----------
__device__ __forceinline__ void gll16(const void* g, void* l) {
    __builtin_amdgcn_global_load_lds(
        (const __attribute__((address_space(1))) unsigned int*)g,
        (__attribute__((address_space(3))) unsigned int*)l,
        16, 0, 0);
}

union Pack8 {
    uint4 u;
    __hip_bfloat16 h[8];
};

__device__ __forceinline__ uint4 cvt8(float4 a, float4 b) {
    Pack8 p;
    p.h[0] = __float2bfloat16(a.x); p.h[1] = __float2bfloat16(a.y);
    p.h[2] = __float2bfloat16(a.z); p.h[3] = __float2bfloat16(a.w);
    p.h[4] = __float2bfloat16(b.x); p.h[5] = __float2bfloat16(b.y);
    p.h[6] = __float2bfloat16(b.z); p.h[7] = __float2bfloat16(b.w);
    return p.u;
}

// ---------- kernel 1: W_enc fp32 -> bf16 ----------
__global__ void k_convert(const float* __restrict__ W, u16* __restrict__ Wb) {
    int idx = blockIdx.x * 256 + threadIdx.x;
    const float4* s = (const float4*)W + (size_t)idx * 2;
    ((uint4*)Wb)[idx] = cvt8(s[0], s[1]);
}

// ---------- kernel 2: att2[b,a] = dec[b,:].W_dec[a,:] + b_enc[a] + b_dec[a] ----------
__global__ void k_att2(const float* __restrict__ dec, const float* __restrict__ Wd,
                       const float* __restrict__ b_enc, const float* __restrict__ b_dec,
                       float* __restrict__ att2f) {
    int b = blockIdx.x;
    int t = threadIdx.x;
    __shared__ float dec_s[DEC_DIM];
    ((float2*)dec_s)[t] = ((const float2*)(dec + (size_t)b * DEC_DIM))[t];
    __syncthreads();
    #pragma unroll
    for (int rep = 0; rep < 2; ++rep) {
        int a = t + rep * 256;
        const float4* w = (const float4*)(Wd + (size_t)a * DEC_DIM);
        float acc = 0.f;
        #pragma unroll 4
        for (int e = 0; e < DEC_DIM / 4; ++e) {
            float4 wv = w[e];
            float4 dv = ((const float4*)dec_s)[e];
            acc += wv.x * dv.x + wv.y * dv.y + wv.z * dv.z + wv.w * dv.w;
        }
        att2f[(size_t)b * ATT_DIM + a] = acc + b_enc[a] + b_dec[a];
    }
}

// ---------- kernel 3: fused GEMM + relu + W_full dot -> att partials ----------
// LDS layout: [row][64] bf16, 8 x 16B slots per 128B row.
// XOR swizzle (T2): data for k-octet c of row r lives at slot c ^ (r&7).
// Staged by pre-swizzling the GLOBAL source per lane (rule #21: both sides).
__global__ void k_gemm(const float* __restrict__ enc, const u16* __restrict__ Wb,
                       const float* __restrict__ att2f, const float* __restrict__ Wfull,
                       float* __restrict__ att_part) {
    const int wg = blockIdx.x;
    const int mb = wg >> 2, nb = wg & 3;     // 4 consecutive blocks share the A panel
    const int t = threadIdx.x;
    const int lane = t & 63, wave = t >> 6;
    const int wm = wave >> 1, wn = wave & 1; // 2x2 wave grid, wave tile 64x64
    const int fr = lane & 15, fq = lane >> 4;

    __shared__ u16 As[128 * 64];  // 16 KB
    __shared__ u16 Bs[128 * 64];  // 16 KB

    f32x4 acc[4][4];
    #pragma unroll
    for (int m = 0; m < 4; ++m)
        #pragma unroll
        for (int n = 0; n < 4; ++n)
            acc[m][n] = (f32x4){0.f, 0.f, 0.f, 0.f};

    // A staging: thread t covers row ar (+s*32), dst slot (t&7); source octet
    // pre-swizzled: c = (t&7) ^ (ar&7)
    const int ar  = t >> 3;
    const int asw = (t & 7) ^ (ar & 7);
    const float* a_src = enc + (size_t)(mb * 128 + ar) * ENC_DIM + asw * 8;
    u16* a_dst = As + ar * 64 + (t & 7) * 8;

    // B staging via global_load_lds: dest linear (base + lane*16B); lane l covers
    // row wave*8 + (l>>3) (+s*32), dst slot l&7; source octet c = (l&7)^(l>>3)
    const int brl = lane >> 3;
    const int bsw = (lane & 7) ^ brl;
    const u16* b_src = Wb + (size_t)(nb * 128 + wave * 8 + brl) * ENC_DIM + bsw * 8;
    u16* b_dst = Bs + wave * 512;   // + s*2048 elems per s; lane*16B added by HW

    // fragment reads: row = (w*64 + m*16 + fr), slot = ((ks<<2)|fq) ^ (fr&7)
    const int r7 = fr & 7;
    const int axo0 = ((fq    ) ^ r7) * 8;   // ks=0
    const int axo1 = ((fq | 4) ^ r7) * 8;   // ks=1
    const u16* a_row = As + (wm * 64 + fr) * 64;
    const u16* b_row = Bs + (wn * 64 + fr) * 64;

    // prefetch A regs for kt=0
    float4 pv0[4], pv1[4];
    #pragma unroll
    for (int s = 0; s < 4; ++s) {
        pv0[s] = *(const float4*)(a_src + (size_t)s * 32 * ENC_DIM);
        pv1[s] = *(const float4*)(a_src + (size_t)s * 32 * ENC_DIM + 4);
    }

    const int NT = ENC_DIM / 64;
    for (int kt = 0; kt < NT; ++kt) {
        __syncthreads();                       // previous tile's compute done
        #pragma unroll
        for (int s = 0; s < 4; ++s)
            *(uint4*)(a_dst + s * 32 * 64) = cvt8(pv0[s], pv1[s]);
        const u16* bs = b_src + kt * 64;
        #pragma unroll
        for (int s = 0; s < 4; ++s)
            gll16(bs + (size_t)s * 32 * ENC_DIM, b_dst + s * 2048);
        __syncthreads();                       // staging visible

        // issue next A loads now: HBM latency hides under compute (T14-lite)
        if (kt + 1 < NT) {
            const float* an = a_src + (kt + 1) * 64;
            #pragma unroll
            for (int s = 0; s < 4; ++s) {
                pv0[s] = *(const float4*)(an + (size_t)s * 32 * ENC_DIM);
                pv1[s] = *(const float4*)(an + (size_t)s * 32 * ENC_DIM + 4);
            }
        }

        #pragma unroll
        for (int ks = 0; ks < 2; ++ks) {
            const int axo = ks ? axo1 : axo0;
            bf16x8 af[4], bfr[4];
            #pragma unroll
            for (int m = 0; m < 4; ++m) af[m]  = *(const bf16x8*)(a_row + m * 1024 + axo);
            #pragma unroll
            for (int n = 0; n < 4; ++n) bfr[n] = *(const bf16x8*)(b_row + n * 1024 + axo);
            #pragma unroll
            for (int m = 0; m < 4; ++m)
                #pragma unroll
                for (int n = 0; n < 4; ++n)
                    acc[m][n] = __builtin_amdgcn_mfma_f32_16x16x32_bf16(af[m], bfr[n], acc[m][n], 0, 0, 0);
        }
    }

    // epilogue: C/D layout col = lane&15, row = (lane>>4)*4 + reg  [m89/m91]
    const int row_base = mb * 128 + wm * 64 + fq * 4;
    const int col_base = nb * 128 + wn * 64 + fr;
    float wf[4];
    #pragma unroll
    for (int n = 0; n < 4; ++n) wf[n] = Wfull[col_base + n * 16];

    #pragma unroll
    for (int m = 0; m < 4; ++m) {
        #pragma unroll
        for (int r = 0; r < 4; ++r) {
            const int grow = row_base + m * 16 + r;
            const int bidx = grow / PIX;
            const float* a2 = att2f + (size_t)bidx * ATT_DIM;
            float ssum = 0.f;
            #pragma unroll
            for (int n = 0; n < 4; ++n) {
                float v = acc[m][n][r] + a2[col_base + n * 16];
                v = fmaxf(v, 0.f);
                ssum += v * wf[n];
            }
            #pragma unroll
            for (int off = 1; off < 16; off <<= 1)
                ssum += __shfl_xor(ssum, off, 64);
            if (fr == 0)
                att_part[(size_t)(nb * 2 + wn) * M_TOTAL + grow] = ssum;
        }
    }
}

// ---------- kernel 4: per-b softmax over 196 + alpha-weighted enc reduction ----------
__global__ void k_soft(const float* __restrict__ att_part, const float* __restrict__ enc,
                       float* __restrict__ out) {
    const int b  = blockIdx.x >> 1;
    const int ec = blockIdx.x & 1;   // e-chunk of 1024
    const int t  = threadIdx.x;
    __shared__ float red[256];
    __shared__ float alpha_s[PIX];

    float myatt = -1e30f;
    if (t < PIX) {
        float s = 0.f;
        #pragma unroll
        for (int j = 0; j < 8; ++j) s += att_part[(size_t)j * M_TOTAL + b * PIX + t];
        myatt = s;
    }
    red[t] = myatt;
    __syncthreads();
    for (int o = 128; o > 0; o >>= 1) {
        if (t < o) red[t] = fmaxf(red[t], red[t + o]);
        __syncthreads();
    }
    const float mx = red[0];
    __syncthreads();
    float e = 0.f;
    if (t < PIX) e = __expf(myatt - mx);
    red[t] = e;
    __syncthreads();
    for (int o = 128; o > 0; o >>= 1) {
        if (t < o) red[t] += red[t + o];
        __syncthreads();
    }
    const float inv = 1.f / red[0];
    if (t < PIX) {
        float al = e * inv;
        alpha_s[t] = al;
        if (ec == 0) out[(size_t)BATCH * ENC_DIM + b * PIX + t] = al;   // alpha output
    }
    __syncthreads();

    float4 acc = {0.f, 0.f, 0.f, 0.f};
    const float* ebase = enc + (size_t)b * PIX * ENC_DIM + ec * 1024 + t * 4;
    #pragma unroll 4
    for (int p = 0; p < PIX; ++p) {
        float4 x = *(const float4*)(ebase + (size_t)p * ENC_DIM);
        float a = alpha_s[p];
        acc.x += a * x.x; acc.y += a * x.y; acc.z += a * x.z; acc.w += a * x.w;
    }
    *(float4*)(out + (size_t)b * ENC_DIM + ec * 1024 + t * 4) = acc;
}

extern "C" void kernel_launch(void* const* d_in, const int* in_sizes, int n_in,
                              void* d_out, int out_size, void* d_ws, size_t ws_size,
                              hipStream_t stream) {
    const float* enc    = (const float*)d_in[0];
    const float* dec    = (const float*)d_in[1];
    const float* W_enc  = (const float*)d_in[2];
    const float* b_enc  = (const float*)d_in[3];
    const float* W_dec  = (const float*)d_in[4];
    const float* b_dec  = (const float*)d_in[5];
    const float* W_full = (const float*)d_in[6];
    // d_in[7] (b_full) unused: softmax is shift-invariant, att is not an output.

    char* ws = (char*)d_ws;
    u16*   Wb    = (u16*)ws;                                    // 2 MB bf16 W_enc
    float* att2f = (float*)(ws + 2 * 1024 * 1024);              // 512 KB
    float* att_p = (float*)(ws + 2 * 1024 * 1024 + 512 * 1024); // 8 * 50176 * 4 B

    hipLaunchKernelGGL(k_convert, dim3(512),     dim3(256), 0, stream, W_enc, Wb);
    hipLaunchKernelGGL(k_att2,    dim3(256),     dim3(256), 0, stream, dec, W_dec, b_enc, b_dec, att2f);
    hipLaunchKernelGGL(k_gemm,    dim3(392 * 4), dim3(256), 0, stream, enc, Wb, att2f, W_full, att_p);
    hipLaunchKernelGGL(k_soft,    dim3(512),     dim3(256), 0, stream, att_p, enc, (float*)d_out);
}

// Round 3
// 338.791 us; speedup vs baseline: 1.4510x; 1.3597x over previous
//
#include <hip/hip_runtime.h>
#include <hip/hip_bf16.h>
#include <stdint.h>

#define ENC_DIM 2048
#define DEC_DIM 512
#define ATT_DIM 512
#define BATCH   256
#define PIX     196
#define M_TOTAL (BATCH*PIX)   // 50176

typedef unsigned short u16;
typedef __attribute__((ext_vector_type(8))) short  bf16x8;
typedef __attribute__((ext_vector_type(4))) float  f32x4;

// ---------- helpers ----------
__device__ __forceinline__ void gll16(const void* g, void* l) {
    __builtin_amdgcn_global_load_lds(
        (const __attribute__((address_space(1))) unsigned int*)g,
        (__attribute__((address_space(3))) unsigned int*)l,
        16, 0, 0);
}

union Pack8 {
    uint4 u;
    __hip_bfloat16 h[8];
};

__device__ __forceinline__ uint4 cvt8(float4 a, float4 b) {
    Pack8 p;
    p.h[0] = __float2bfloat16(a.x); p.h[1] = __float2bfloat16(a.y);
    p.h[2] = __float2bfloat16(a.z); p.h[3] = __float2bfloat16(a.w);
    p.h[4] = __float2bfloat16(b.x); p.h[5] = __float2bfloat16(b.y);
    p.h[6] = __float2bfloat16(b.z); p.h[7] = __float2bfloat16(b.w);
    return p.u;
}

// ---------- kernel 1: W_enc fp32 -> bf16 ----------
__global__ void k_convert(const float* __restrict__ W, u16* __restrict__ Wb) {
    int idx = blockIdx.x * 256 + threadIdx.x;
    const float4* s = (const float4*)W + (size_t)idx * 2;
    ((uint4*)Wb)[idx] = cvt8(s[0], s[1]);
}

// ---------- kernel 2: att2[b,a] = dec[b,:].W_dec[a,:] + b_enc[a] + b_dec[a] ----------
__global__ void k_att2(const float* __restrict__ dec, const float* __restrict__ Wd,
                       const float* __restrict__ b_enc, const float* __restrict__ b_dec,
                       float* __restrict__ att2f) {
    int b = blockIdx.x;
    int t = threadIdx.x;
    __shared__ float dec_s[DEC_DIM];
    ((float2*)dec_s)[t] = ((const float2*)(dec + (size_t)b * DEC_DIM))[t];
    __syncthreads();
    #pragma unroll
    for (int rep = 0; rep < 2; ++rep) {
        int a = t + rep * 256;
        const float4* w = (const float4*)(Wd + (size_t)a * DEC_DIM);
        float acc = 0.f;
        #pragma unroll 4
        for (int e = 0; e < DEC_DIM / 4; ++e) {
            float4 wv = w[e];
            float4 dv = ((const float4*)dec_s)[e];
            acc += wv.x * dv.x + wv.y * dv.y + wv.z * dv.z + wv.w * dv.w;
        }
        att2f[(size_t)b * ATT_DIM + a] = acc + b_enc[a] + b_dec[a];
    }
}

// ---------- kernel 3: fused GEMM + relu + W_full dot -> att partials ----------
// Pipelined: dbuf LDS, raw s_barrier + counted vmcnt (T3/T4), 2-deep A prefetch,
// XOR-swizzled LDS (T2, both-sides), XCD-chunked grid (T1).
#define NT (ENC_DIM / 64)

#define ISSUE_A(KT, va, vb) do { const float* _p = a_src + (size_t)(KT) * 64;          \
    _Pragma("unroll") for (int s = 0; s < 4; ++s) {                                    \
        va[s] = *(const float4*)(_p + (size_t)s * 32 * ENC_DIM);                       \
        vb[s] = *(const float4*)(_p + (size_t)s * 32 * ENC_DIM + 4); } } while (0)

#define WRITE_A(BUF, va, vb) do { _Pragma("unroll") for (int s = 0; s < 4; ++s)        \
    *(uint4*)(As[BUF] + a_dst_off + s * 32 * 64) = cvt8(va[s], vb[s]); } while (0)

#define STAGE_B(KT, BUF) do { const u16* _b = b_src + (size_t)(KT) * 64;               \
    _Pragma("unroll") for (int s = 0; s < 4; ++s)                                      \
        gll16(_b + (size_t)s * 32 * ENC_DIM, Bs[BUF] + b_dst_off + s * 2048); } while (0)

#define COMPUTE(BUF) do {                                                              \
    const u16* a_row = As[BUF] + a_row_off;                                            \
    const u16* b_row = Bs[BUF] + b_row_off;                                            \
    _Pragma("unroll") for (int ks = 0; ks < 2; ++ks) {                                 \
        const int axo = ks ? axo1 : axo0;                                              \
        bf16x8 af[4], bfr[4];                                                          \
        _Pragma("unroll") for (int m = 0; m < 4; ++m)                                  \
            af[m]  = *(const bf16x8*)(a_row + m * 1024 + axo);                         \
        _Pragma("unroll") for (int n = 0; n < 4; ++n)                                  \
            bfr[n] = *(const bf16x8*)(b_row + n * 1024 + axo);                         \
        __builtin_amdgcn_s_setprio(1);                                                 \
        _Pragma("unroll") for (int m = 0; m < 4; ++m)                                  \
            _Pragma("unroll") for (int n = 0; n < 4; ++n)                              \
                acc[m][n] = __builtin_amdgcn_mfma_f32_16x16x32_bf16(af[m], bfr[n], acc[m][n], 0, 0, 0); \
        __builtin_amdgcn_s_setprio(0); } } while (0)

#define WAIT8  asm volatile("s_waitcnt vmcnt(8) lgkmcnt(0)" ::: "memory")
#define WAIT0  asm volatile("s_waitcnt vmcnt(0) lgkmcnt(0)" ::: "memory")
#define SBAR   __builtin_amdgcn_s_barrier()
#define SCHED0 __builtin_amdgcn_sched_barrier(0)

__global__ void __launch_bounds__(256, 2)
k_gemm(const float* __restrict__ enc, const u16* __restrict__ Wb,
       const float* __restrict__ att2f, const float* __restrict__ Wfull,
       float* __restrict__ att_part) {
    const int bid = blockIdx.x;
    const int wg = (bid & 7) * 196 + (bid >> 3);   // XCD-chunked, bijective (1568 = 8*196)
    const int mb = wg >> 2, nb = wg & 3;           // 4 blocks sharing an A panel -> same XCD
    const int t = threadIdx.x;
    const int lane = t & 63, wave = t >> 6;
    const int wm = wave >> 1, wn = wave & 1;
    const int fr = lane & 15, fq = lane >> 4;

    __shared__ u16 As[2][128 * 64];  // 2 x 16 KB
    __shared__ u16 Bs[2][128 * 64];  // 2 x 16 KB

    f32x4 acc[4][4];
    #pragma unroll
    for (int m = 0; m < 4; ++m)
        #pragma unroll
        for (int n = 0; n < 4; ++n)
            acc[m][n] = (f32x4){0.f, 0.f, 0.f, 0.f};

    // A staging: thread t covers row ar (+s*32), dst slot (t&7); src octet pre-swizzled
    const int ar  = t >> 3;
    const int asw = (t & 7) ^ (ar & 7);
    const float* a_src = enc + (size_t)(mb * 128 + ar) * ENC_DIM + asw * 8;
    const int a_dst_off = ar * 64 + (t & 7) * 8;

    // B staging via global_load_lds: linear dest, pre-swizzled global source
    const int brl = lane >> 3;
    const int bsw = (lane & 7) ^ brl;
    const u16* b_src = Wb + (size_t)(nb * 128 + wave * 8 + brl) * ENC_DIM + bsw * 8;
    const int b_dst_off = wave * 512;   // + lane*16B added by HW

    // fragment reads: row = (w*64 + f*16 + fr), slot = ((ks<<2)|fq) ^ (fr&7)
    const int r7 = fr & 7;
    const int axo0 = ((fq    ) ^ r7) * 8;
    const int axo1 = ((fq | 4) ^ r7) * 8;
    const int a_row_off = (wm * 64 + fr) * 64;
    const int b_row_off = (wn * 64 + fr) * 64;

    float4 e0a[4], e0b[4], e1a[4], e1b[4];   // 2-deep A prefetch (parity-named, rule #20)

    // ---- prologue ----
    ISSUE_A(0, e0a, e0b);
    STAGE_B(0, 0);
    SCHED0;
    WRITE_A(0, e0a, e0b);        // compiler auto-waits the A(0) regs
    ISSUE_A(1, e1a, e1b);
    WAIT8;                       // drain gll16(0); A(1) x8 stays in flight
    SCHED0;
    SBAR;
    SCHED0;

    for (int kt = 0; kt < NT; kt += 2) {
        // ---- even iter: CUR=0, NXT=1 ----
        {
            if (kt + 1 < NT) STAGE_B(kt + 1, 1);
            SCHED0;                            // pin: gll16 before A-issue (vmcnt order)
            if (kt + 2 < NT) ISSUE_A(kt + 2, e0a, e0b);
            COMPUTE(0);
            if (kt + 1 < NT) {
                WRITE_A(1, e1a, e1b);
                if (kt + 2 < NT) { WAIT8; } else { WAIT0; }
                SCHED0;
                SBAR;
                SCHED0;
            }
        }
        // ---- odd iter: CUR=1, NXT=0 ----
        if (kt + 1 < NT) {
            if (kt + 2 < NT) STAGE_B(kt + 2, 0);
            SCHED0;
            if (kt + 3 < NT) ISSUE_A(kt + 3, e1a, e1b);
            COMPUTE(1);
            if (kt + 2 < NT) {
                WRITE_A(0, e0a, e0b);
                if (kt + 3 < NT) { WAIT8; } else { WAIT0; }
                SCHED0;
                SBAR;
                SCHED0;
            }
        }
    }

    // epilogue: C/D layout col = lane&15, row = (lane>>4)*4 + reg  [m89/m91]
    const int row_base = mb * 128 + wm * 64 + fq * 4;
    const int col_base = nb * 128 + wn * 64 + fr;
    float wf[4];
    #pragma unroll
    for (int n = 0; n < 4; ++n) wf[n] = Wfull[col_base + n * 16];

    #pragma unroll
    for (int m = 0; m < 4; ++m) {
        #pragma unroll
        for (int r = 0; r < 4; ++r) {
            const int grow = row_base + m * 16 + r;
            const int bidx = grow / PIX;
            const float* a2 = att2f + (size_t)bidx * ATT_DIM;
            float ssum = 0.f;
            #pragma unroll
            for (int n = 0; n < 4; ++n) {
                float v = acc[m][n][r] + a2[col_base + n * 16];
                v = fmaxf(v, 0.f);
                ssum += v * wf[n];
            }
            #pragma unroll
            for (int off = 1; off < 16; off <<= 1)
                ssum += __shfl_xor(ssum, off, 64);
            if (fr == 0)
                att_part[(size_t)(nb * 2 + wn) * M_TOTAL + grow] = ssum;
        }
    }
}

// ---------- kernel 4: per-b softmax over 196 + alpha-weighted enc reduction ----------
__global__ void k_soft(const float* __restrict__ att_part, const float* __restrict__ enc,
                       float* __restrict__ out) {
    const int b  = blockIdx.x >> 1;
    const int ec = blockIdx.x & 1;   // e-chunk of 1024
    const int t  = threadIdx.x;
    __shared__ float red[256];
    __shared__ float alpha_s[PIX];

    float myatt = -1e30f;
    if (t < PIX) {
        float s = 0.f;
        #pragma unroll
        for (int j = 0; j < 8; ++j) s += att_part[(size_t)j * M_TOTAL + b * PIX + t];
        myatt = s;
    }
    red[t] = myatt;
    __syncthreads();
    for (int o = 128; o > 0; o >>= 1) {
        if (t < o) red[t] = fmaxf(red[t], red[t + o]);
        __syncthreads();
    }
    const float mx = red[0];
    __syncthreads();
    float e = 0.f;
    if (t < PIX) e = __expf(myatt - mx);
    red[t] = e;
    __syncthreads();
    for (int o = 128; o > 0; o >>= 1) {
        if (t < o) red[t] += red[t + o];
        __syncthreads();
    }
    const float inv = 1.f / red[0];
    if (t < PIX) {
        float al = e * inv;
        alpha_s[t] = al;
        if (ec == 0) out[(size_t)BATCH * ENC_DIM + b * PIX + t] = al;   // alpha output
    }
    __syncthreads();

    float4 acc = {0.f, 0.f, 0.f, 0.f};
    const float* ebase = enc + (size_t)b * PIX * ENC_DIM + ec * 1024 + t * 4;
    #pragma unroll 4
    for (int p = 0; p < PIX; ++p) {
        float4 x = *(const float4*)(ebase + (size_t)p * ENC_DIM);
        float a = alpha_s[p];
        acc.x += a * x.x; acc.y += a * x.y; acc.z += a * x.z; acc.w += a * x.w;
    }
    *(float4*)(out + (size_t)b * ENC_DIM + ec * 1024 + t * 4) = acc;
}

extern "C" void kernel_launch(void* const* d_in, const int* in_sizes, int n_in,
                              void* d_out, int out_size, void* d_ws, size_t ws_size,
                              hipStream_t stream) {
    const float* enc    = (const float*)d_in[0];
    const float* dec    = (const float*)d_in[1];
    const float* W_enc  = (const float*)d_in[2];
    const float* b_enc  = (const float*)d_in[3];
    const float* W_dec  = (const float*)d_in[4];
    const float* b_dec  = (const float*)d_in[5];
    const float* W_full = (const float*)d_in[6];
    // d_in[7] (b_full) unused: softmax is shift-invariant, att is not an output.

    char* ws = (char*)d_ws;
    u16*   Wb    = (u16*)ws;                                    // 2 MB bf16 W_enc
    float* att2f = (float*)(ws + 2 * 1024 * 1024);              // 512 KB
    float* att_p = (float*)(ws + 2 * 1024 * 1024 + 512 * 1024); // 8 * 50176 * 4 B

    hipLaunchKernelGGL(k_convert, dim3(512),     dim3(256), 0, stream, W_enc, Wb);
    hipLaunchKernelGGL(k_att2,    dim3(256),     dim3(256), 0, stream, dec, W_dec, b_enc, b_dec, att2f);
    hipLaunchKernelGGL(k_gemm,    dim3(392 * 4), dim3(256), 0, stream, enc, Wb, att2f, W_full, att_p);
    hipLaunchKernelGGL(k_soft,    dim3(512),     dim3(256), 0, stream, att_p, enc, (float*)d_out);
}